// Round 3
// baseline (131.251 us; speedup 1.0000x reference)
//
#include <hip/hip_runtime.h>
#include <hip/hip_bf16.h>

// Problem constants (fixed shapes from the reference)
#define DIN   2048
#define DOUT  2048
#define NTOK  2048
#define NE    8
#define TOPK  2
#define NK    (NTOK*TOPK)   // 4096 flat (token,slot) rows
#define BM    128
#define BN    128
#define BK    64
#define KTILES (DIN/BK)     // 32
#define MAXMT  (NK/BM + NE) // 40 worst-case M-tiles across ragged experts

#define WEL   (NE*DOUT*DIN)   // 33554432 weight elements
#define XEL   (NTOK*DIN)      // 4194304 input elements

typedef unsigned short u16;
typedef __attribute__((ext_vector_type(8))) short bf16x8;
typedef __attribute__((ext_vector_type(4))) float f32x4;

// fp32 -> bf16 pair pack: round-half-away (add 0x8000 to bit pattern), then
// v_perm_b32 grabs the two high halves. 3 VALU per pair.
__device__ __forceinline__ unsigned pack2rn(float a, float b) {
    union { float f; unsigned u; } x, y; x.f = a; y.f = b;
    return __builtin_amdgcn_perm(y.u + 0x8000u, x.u + 0x8000u, 0x07060302u);
}

// async global -> LDS, 16 bytes per lane (wave-uniform LDS base + lane*16)
__device__ __forceinline__ void gl_lds16(const void* g, void* l) {
    __builtin_amdgcn_global_load_lds(
        (const __attribute__((address_space(1))) void*)g,
        (__attribute__((address_space(3)))       void*)l, 16, 0, 0);
}

// ---------------- Pass 1: fp32 -> bf16 convert (weight + inputs) ----------------
__global__ __launch_bounds__(256) void cvt_bf16(
    const float* __restrict__ w, const float* __restrict__ x,
    u16* __restrict__ wbf, u16* __restrict__ xbf)
{
    const size_t nch = (size_t)(WEL + XEL) / 8;
    for (size_t c = (size_t)blockIdx.x * blockDim.x + threadIdx.x; c < nch;
         c += (size_t)gridDim.x * blockDim.x) {
        const float* src; u16* dst; size_t off;
        if (c < (size_t)WEL / 8) { src = w; dst = wbf; off = c * 8; }
        else                     { src = x; dst = xbf; off = (c - (size_t)WEL / 8) * 8; }
        float4 f0 = *(const float4*)(src + off);
        float4 f1 = *(const float4*)(src + off + 4);
        uint4 pk;
        pk.x = pack2rn(f0.x, f0.y); pk.y = pack2rn(f0.z, f0.w);
        pk.z = pack2rn(f1.x, f1.y); pk.w = pack2rn(f1.z, f1.w);
        *(uint4*)(dst + off) = pk;
    }
}

// ---------------- Pass 2: bf16 grouped GEMM, m97-style 2-phase ----------------
// One block = 128 sorted rows x 128 d_out cols. A rows gathered via per-lane
// global_load_lds source addresses; T2 swizzle folded into source chunk index.
__global__ __launch_bounds__(256, 2) void moe_gemm_split(
    const u16* __restrict__ xb,            // [NTOK][DIN] bf16
    const u16* __restrict__ wb,            // [NE][DOUT][DIN] bf16
    const int* __restrict__ sorted_scattered_idxs,
    const int* __restrict__ expert_offsets,
    const float* __restrict__ gates,
    float*     __restrict__ out)
{
    __shared__ u16 As[2][BM * BK];
    __shared__ u16 Bs[2][BN * BK];
    __shared__ int   s_tok[BM];
    __shared__ float s_gate[BM];

    const int mt = blockIdx.y;
    const int n0 = blockIdx.x * BN;

    int e = -1, m0 = 0, cnt = 0;
    {
        int acc = 0, prev = 0;
        for (int i = 0; i < NE; ++i) {
            int end = expert_offsets[i];
            int c = end - prev;
            int t = (c + BM - 1) / BM;
            if (mt < acc + t) {
                e = i; m0 = prev + (mt - acc) * BM;
                cnt = end - m0; if (cnt > BM) cnt = BM;
                break;
            }
            acc += t; prev = end;
        }
    }
    if (e < 0) return;

    const int tid = threadIdx.x;
    if (tid < BM) {
        int idx = (tid < cnt) ? (m0 + tid) : m0;   // clamp ragged rows to a valid gather
        int p = sorted_scattered_idxs[idx];        // flat slot id = token*TOPK + slot
        s_tok[tid]  = p;
        s_gate[tid] = gates[p];
    }
    __syncthreads();

    const int wid = tid >> 6, lane = tid & 63;

    // ---- staging geometry: wave wid stages rows [wid*32, wid*32+32), 4 segs of 8 rows.
    // LDS is linear; the T2 swizzle is applied by permuting the SOURCE chunk.
    const u16* wbase = wb + (size_t)e * DOUT * DIN;
    const u16* aSrc[4];
    const u16* bSrc[4];
    #pragma unroll
    for (int s = 0; s < 4; ++s) {
        int r  = wid * 32 + s * 8 + (lane >> 3);
        int cg = (lane & 7) ^ (r & 7);             // source chunk so LDS[r][cc] holds chunk cc^(r&7)
        aSrc[s] = xb + (size_t)(s_tok[r] >> 1) * DIN + cg * 8;
        bSrc[s] = wbase + (size_t)(n0 + r) * DIN + cg * 8;
    }
    const int segoff = wid * 32 * BK;              // LDS base (ushorts) of this wave's region

    // ---- fragment read offsets (swizzled col), ushort units
    const int g = lane >> 4, lr = lane & 15;
    const int wm = (wid >> 1) * 64, wn = (wid & 1) * 64;
    int aoff[2][4], boff[2][4];
    #pragma unroll
    for (int ks = 0; ks < 2; ++ks)
        #pragma unroll
        for (int i = 0; i < 4; ++i) {
            int cc = (ks * 4 + g) ^ (lr & 7);
            aoff[ks][i] = (wm + i * 16 + lr) * BK + cc * 8;
            boff[ks][i] = (wn + i * 16 + lr) * BK + cc * 8;
        }

    f32x4 acc[4][4];
    #pragma unroll
    for (int i = 0; i < 4; ++i)
        #pragma unroll
        for (int j = 0; j < 4; ++j) acc[i][j] = (f32x4)0.0f;

    // ---- prologue: stage K-tile 0 into buffer 0
    #pragma unroll
    for (int s = 0; s < 4; ++s) {
        gl_lds16(aSrc[s], &As[0][segoff + s * 8 * BK]);
        gl_lds16(bSrc[s], &Bs[0][segoff + s * 8 * BK]);
    }
    __syncthreads();   // drains vmcnt before barrier

    int cur = 0;
    for (int kt = 0; kt < KTILES; ++kt) {
        // issue next tile's staging first; loads fly during ds_read + MFMA
        if (kt + 1 < KTILES) {
            const int kof = (kt + 1) * BK;
            #pragma unroll
            for (int s = 0; s < 4; ++s) {
                gl_lds16(aSrc[s] + kof, &As[cur ^ 1][segoff + s * 8 * BK]);
                gl_lds16(bSrc[s] + kof, &Bs[cur ^ 1][segoff + s * 8 * BK]);
            }
        }
        // compute current tile: 2 k-slices x 16 MFMA
        #pragma unroll
        for (int ks = 0; ks < 2; ++ks) {
            bf16x8 a[4], b[4];
            #pragma unroll
            for (int i = 0; i < 4; ++i) {
                a[i] = *(const bf16x8*)(&As[cur][aoff[ks][i]]);
                b[i] = *(const bf16x8*)(&Bs[cur][boff[ks][i]]);
            }
            #pragma unroll
            for (int i = 0; i < 4; ++i)
                #pragma unroll
                for (int j = 0; j < 4; ++j)
                    acc[i][j] = __builtin_amdgcn_mfma_f32_16x16x32_bf16(a[i], b[j], acc[i][j], 0, 0, 0);
        }
        __syncthreads();   // drain stage vmcnt + lds reads, then barrier
        cur ^= 1;
    }

    // ---- epilogue: out[token] += gate * y
    #pragma unroll
    for (int i = 0; i < 4; ++i) {
        #pragma unroll
        for (int j2 = 0; j2 < 4; ++j2) {
            int lrow = wm + i * 16 + g * 4 + j2;
            if (lrow < cnt) {
                int   p  = s_tok[lrow];
                float gf = s_gate[lrow];
                float* orow = out + (size_t)(p >> 1) * DOUT + n0 + wn;
                #pragma unroll
                for (int nf = 0; nf < 4; ++nf)
                    atomicAdd(orow + nf * 16 + lr, gf * acc[i][nf][j2]);
            }
        }
    }
}

// ---------------- Fallback: round-2 fused kernel (used if ws too small) ----------------
__global__ __launch_bounds__(256, 3) void moe_gemm_fused(
    const float* __restrict__ inputs, const float* __restrict__ weight,
    const int* __restrict__ sorted_scattered_idxs, const int* __restrict__ expert_offsets,
    const float* __restrict__ gates, float* __restrict__ out)
{
    __shared__ u16 As[BM * BK];
    __shared__ u16 Bs[BN * BK];
    __shared__ int   s_tok[BM];
    __shared__ float s_gate[BM];

    const int mt = blockIdx.y;
    const int n0 = blockIdx.x * BN;
    int e = -1, m0 = 0, cnt = 0;
    {
        int acc = 0, prev = 0;
        for (int i = 0; i < NE; ++i) {
            int end = expert_offsets[i];
            int c = end - prev;
            int t = (c + BM - 1) / BM;
            if (mt < acc + t) {
                e = i; m0 = prev + (mt - acc) * BM;
                cnt = end - m0; if (cnt > BM) cnt = BM;
                break;
            }
            acc += t; prev = end;
        }
    }
    if (e < 0) return;

    const int tid = threadIdx.x;
    if (tid < BM) {
        int idx = (tid < cnt) ? (m0 + tid) : m0;
        int p = sorted_scattered_idxs[idx];
        s_tok[tid]  = p;
        s_gate[tid] = gates[p];
    }
    __syncthreads();

    const int ch  = tid & 7;
    const int r0  = tid >> 3;
    const int sch = ch ^ (r0 & 7);
    const float* wbase = weight + (size_t)e * DOUT * DIN;
    const float* ap[4]; const float* bp[4];
    #pragma unroll
    for (int i = 0; i < 4; ++i) {
        int r = r0 + 32 * i;
        ap[i] = inputs + (size_t)(s_tok[r] >> 1) * DIN + ch * 8;
        bp[i] = wbase + (size_t)(n0 + r) * DIN + ch * 8;
    }
    u16* aw = &As[r0 * BK + sch * 8];
    u16* bw = &Bs[r0 * BK + sch * 8];

    const int wid = tid >> 6, lane = tid & 63;
    const int wm = (wid >> 1) * 64, wn = (wid & 1) * 64;
    const int g  = lane >> 4, lr = lane & 15;

    f32x4 acc[4][4];
    #pragma unroll
    for (int i = 0; i < 4; ++i)
        #pragma unroll
        for (int j = 0; j < 4; ++j) acc[i][j] = (f32x4)0.0f;

    float4 pa[4][2], pb[4][2];
    #pragma unroll
    for (int i = 0; i < 4; ++i) {
        pa[i][0] = *(const float4*)(ap[i] + 0); pa[i][1] = *(const float4*)(ap[i] + 4);
        pb[i][0] = *(const float4*)(bp[i] + 0); pb[i][1] = *(const float4*)(bp[i] + 4);
    }
    for (int kt = 0; kt < KTILES; ++kt) {
        __syncthreads();
        #pragma unroll
        for (int i = 0; i < 4; ++i) {
            uint4 va, vb;
            va.x = pack2rn(pa[i][0].x, pa[i][0].y); va.y = pack2rn(pa[i][0].z, pa[i][0].w);
            va.z = pack2rn(pa[i][1].x, pa[i][1].y); va.w = pack2rn(pa[i][1].z, pa[i][1].w);
            *(uint4*)(aw + i * 32 * BK) = va;
            vb.x = pack2rn(pb[i][0].x, pb[i][0].y); vb.y = pack2rn(pb[i][0].z, pb[i][0].w);
            vb.z = pack2rn(pb[i][1].x, pb[i][1].y); vb.w = pack2rn(pb[i][1].z, pb[i][1].w);
            *(uint4*)(bw + i * 32 * BK) = vb;
        }
        __syncthreads();
        if (kt + 1 < KTILES) {
            const int kof = (kt + 1) * BK;
            #pragma unroll
            for (int i = 0; i < 4; ++i) {
                pa[i][0] = *(const float4*)(ap[i] + kof); pa[i][1] = *(const float4*)(ap[i] + kof + 4);
                pb[i][0] = *(const float4*)(bp[i] + kof); pb[i][1] = *(const float4*)(bp[i] + kof + 4);
            }
        }
        #pragma unroll
        for (int ks = 0; ks < 2; ++ks) {
            bf16x8 a[4], b[4];
            #pragma unroll
            for (int i = 0; i < 4; ++i) {
                int ra = wm + i * 16 + lr; int ca = (ks * 4 + g) ^ (ra & 7);
                a[i] = *(const bf16x8*)(&As[ra * BK + ca * 8]);
                int rb = wn + i * 16 + lr; int cb = (ks * 4 + g) ^ (rb & 7);
                b[i] = *(const bf16x8*)(&Bs[rb * BK + cb * 8]);
            }
            #pragma unroll
            for (int i = 0; i < 4; ++i)
                #pragma unroll
                for (int j = 0; j < 4; ++j)
                    acc[i][j] = __builtin_amdgcn_mfma_f32_16x16x32_bf16(a[i], b[j], acc[i][j], 0, 0, 0);
        }
    }
    #pragma unroll
    for (int i = 0; i < 4; ++i) {
        #pragma unroll
        for (int j2 = 0; j2 < 4; ++j2) {
            int lrow = wm + i * 16 + g * 4 + j2;
            if (lrow < cnt) {
                int   p  = s_tok[lrow];
                float gf = s_gate[lrow];
                float* orow = out + (size_t)(p >> 1) * DOUT + n0 + wn;
                #pragma unroll
                for (int nf = 0; nf < 4; ++nf)
                    atomicAdd(orow + nf * 16 + lr, gf * acc[i][nf][j2]);
            }
        }
    }
}

extern "C" void kernel_launch(void* const* d_in, const int* in_sizes, int n_in,
                              void* d_out, int out_size, void* d_ws, size_t ws_size,
                              hipStream_t stream) {
    const float* inputs  = (const float*)d_in[0];
    const float* weight  = (const float*)d_in[1];
    const int*   ssi     = (const int*)d_in[4];
    const int*   eoff    = (const int*)d_in[6];
    const float* gates   = (const float*)d_in[7];
    float* out = (float*)d_out;

    hipMemsetAsync(out, 0, (size_t)out_size * sizeof(float), stream);
    dim3 grid(DOUT / BN, MAXMT);

    const size_t need = ((size_t)WEL + (size_t)XEL) * sizeof(u16);  // 75.5 MB
    if (ws_size >= need) {
        u16* wbf = (u16*)d_ws;
        u16* xbf = wbf + (size_t)WEL;
        cvt_bf16<<<2048, 256, 0, stream>>>(weight, inputs, wbf, xbf);
        moe_gemm_split<<<grid, 256, 0, stream>>>(xbf, wbf, ssi, eoff, gates, out);
    } else {
        moe_gemm_fused<<<grid, 256, 0, stream>>>(inputs, weight, ssi, eoff, gates, out);
    }
}